// Round 11
// baseline (431.873 us; speedup 1.0000x reference)
//
#include <hip/hip_runtime.h>
#include <hip/hip_bf16.h>
#include <cstdint>

typedef __bf16 bf16_t;
typedef __bf16 bf16x8 __attribute__((ext_vector_type(8)));
typedef __bf16 bf16x4 __attribute__((ext_vector_type(4)));
typedef float  f32x4  __attribute__((ext_vector_type(4)));

#define B_  2
#define S_  2048
#define D_  2048
#define H_  16
#define DH_ 128
#define LDQ 6144   // QKV concat row stride

// ---------------------------------------------------------------------------
// async global->LDS (16B per lane, dest = wave-uniform base + lane*16)
__device__ __forceinline__ void gload_lds16(const bf16_t* g, bf16_t* l) {
    __builtin_amdgcn_global_load_lds(
        (const __attribute__((address_space(1))) void*)g,
        (__attribute__((address_space(3))) void*)l, 16, 0, 0);
}

#define BAR  do { asm volatile("" ::: "memory"); __builtin_amdgcn_s_barrier(); \
                  asm volatile("" ::: "memory"); } while (0)

// ---------------------------------------------------------------------------
// fused fp32 -> bf16 cast of all 5 inputs (X, Wq, Wk, Wv -> Wqkv concat, Wo)
__global__ __launch_bounds__(256)
void cast_all_k(const float* __restrict__ X,  const float* __restrict__ Wq,
                const float* __restrict__ Wk, const float* __restrict__ Wv,
                const float* __restrict__ Wo,
                bf16_t* __restrict__ Xb, bf16_t* __restrict__ Wqkv,
                bf16_t* __restrict__ Wob) {
    long bid = blockIdx.x;
    const float* src; bf16_t* dst; long off;
    if      (bid <  8192) { src = X;  dst = Xb;             off = bid;         }
    else if (bid < 12288) { src = Wq; dst = Wqkv;           off = bid - 8192;  }
    else if (bid < 16384) { src = Wk; dst = Wqkv + 4194304; off = bid - 12288; }
    else if (bid < 20480) { src = Wv; dst = Wqkv + 8388608; off = bid - 16384; }
    else                  { src = Wo; dst = Wob;            off = bid - 20480; }
    long i = (off * 256 + threadIdx.x) * 4;
    float4 v = *(const float4*)(src + i);
    bf16x4 o = {(bf16_t)v.x, (bf16_t)v.y, (bf16_t)v.z, (bf16_t)v.w};
    *(bf16x4*)(dst + i) = o;
}

// ---------------------------------------------------------------------------
// m201-geometry NT GEMM: 256x256x64 tile, 8 waves (2M x 4N), wave tile 128x64.
// LDS: 2 dbuf x 2 half x [128][64] bf16 per operand = 128 KiB, chunk-XOR swz.
// Per K-tile: 4 phases (quadrants A0B0, A0B1, A1B1, A1B0), each operand half
// LDS-read once and held in regs. Stage t+2 into the LIVE buffer: B-halves at
// ph3 (B reads done at ph2), A-halves at ph4 (A reads done at ph3).
// Boundary: vmcnt(8) -- t+2's 8 loads in flight; t+1's (issued one K-tile
// earlier, 5-6 phases of slack) are drained.
#define LDS8(s, row, chunk) \
    (*(const bf16x8*)((s) + (row) * 64 + ((((chunk) ^ ((row) & 7))) << 3)))

template<bool C_BF16>
__global__ __launch_bounds__(512, 1)
void gemm8(const bf16_t* __restrict__ A, int lda,
           const bf16_t* __restrict__ B, int ldb,
           void* __restrict__ Cp, int ldc, int K, int nbx) {
    __shared__ bf16_t sA[2][2][128 * 64];
    __shared__ bf16_t sB[2][2][128 * 64];

    const int tid  = threadIdx.x;
    const int w    = tid >> 6;
    const int lane = tid & 63;
    const int fr   = lane & 15;
    const int hi   = lane >> 4;
    const int wm   = w >> 2;        // 0..1: A-half / 128-row group
    const int wn   = w & 3;         // 0..3: 64-col strip
    const int bh2  = wn >> 1;       // B-half
    const int brow = (wn & 1) * 64; // strip base within B-half

    const int nwg = gridDim.x;
    const int lin = blockIdx.x;
    const int swz = (lin & 7) * (nwg >> 3) + (lin >> 3);
    const long bm = (long)(swz / nbx) * 256;
    const long bn = (long)(swz % nbx) * 256;

    const int srow = tid >> 3;                       // 0..63
    const int scol = ((tid & 7) ^ (srow & 7)) * 8;   // inverse-swizzled source
    const bf16_t* Agp = A + (bm + srow) * (long)lda + scol;
    const bf16_t* Bgp = B + (bn + srow) * (long)ldb + scol;

    // stage one operand's full K-tile: 2 halves x 2 gloads = 4 loads/thread
#define STAGE_A2(c, kt) { _Pragma("unroll") \
    for (int h2 = 0; h2 < 2; ++h2) { _Pragma("unroll") \
      for (int p = 0; p < 2; ++p) \
        gload_lds16(Agp + (long)(h2 * 128 + p * 64) * lda + ((long)(kt) << 6), \
                    &sA[c][h2][(p * 64) * 64 + w * 512]); } }
#define STAGE_B2(c, kt) { _Pragma("unroll") \
    for (int h2 = 0; h2 < 2; ++h2) { _Pragma("unroll") \
      for (int p = 0; p < 2; ++p) \
        gload_lds16(Bgp + (long)(h2 * 128 + p * 64) * ldb + ((long)(kt) << 6), \
                    &sB[c][h2][(p * 64) * 64 + w * 512]); } }

#define MM16(am, bm_, m0, n0) { _Pragma("unroll") \
    for (int mi = 0; mi < 4; ++mi) { _Pragma("unroll") \
      for (int ni = 0; ni < 2; ++ni) { _Pragma("unroll") \
        for (int ks = 0; ks < 2; ++ks) \
          acc[(m0) + mi][(n0) + ni] = __builtin_amdgcn_mfma_f32_16x16x32_bf16( \
              am[mi][ks], bm_[ni][ks], acc[(m0) + mi][(n0) + ni], 0, 0, 0); } } }

    f32x4 acc[8][4] = {};
    const int nkt = K >> 6;   // >= 2

    // prologue: tiles 0 and 1
    STAGE_A2(0, 0) STAGE_B2(0, 0)
    STAGE_A2(1, 1) STAGE_B2(1, 1)
    asm volatile("s_waitcnt vmcnt(8)" ::: "memory");
    BAR;

    for (int t = 0; t < nkt; ++t) {
        const int c = t & 1;
        const bool st2 = t + 2 < nkt;
        const bf16_t* sAh = sA[c][wm];
        const bf16_t* sBh = sB[c][bh2];
        bf16x8 alo[4][2], ahi[4][2], blo[2][2], bhi[2][2];

        // ---- phase 1: ds A-lo (8) + B-lo (4); MFMA A0B0
#pragma unroll
        for (int mi = 0; mi < 4; ++mi)
#pragma unroll
            for (int ks = 0; ks < 2; ++ks)
                alo[mi][ks] = LDS8(sAh, mi * 16 + fr, ks * 4 + hi);
#pragma unroll
        for (int ni = 0; ni < 2; ++ni)
#pragma unroll
            for (int ks = 0; ks < 2; ++ks)
                blo[ni][ks] = LDS8(sBh, brow + ni * 16 + fr, ks * 4 + hi);
        BAR;
        __builtin_amdgcn_s_setprio(1);
        MM16(alo, blo, 0, 0);
        __builtin_amdgcn_s_setprio(0);
        BAR;

        // ---- phase 2: ds B-hi (4); MFMA A0B1
#pragma unroll
        for (int ni = 0; ni < 2; ++ni)
#pragma unroll
            for (int ks = 0; ks < 2; ++ks)
                bhi[ni][ks] = LDS8(sBh, brow + (2 + ni) * 16 + fr, ks * 4 + hi);
        BAR;
        __builtin_amdgcn_s_setprio(1);
        MM16(alo, bhi, 0, 2);
        __builtin_amdgcn_s_setprio(0);
        BAR;

        // ---- phase 3: ds A-hi (8); stage B(t+2) into live buf; MFMA A1B1
#pragma unroll
        for (int mi = 0; mi < 4; ++mi)
#pragma unroll
            for (int ks = 0; ks < 2; ++ks)
                ahi[mi][ks] = LDS8(sAh, (4 + mi) * 16 + fr, ks * 4 + hi);
        if (st2) STAGE_B2(c, t + 2)
        BAR;
        __builtin_amdgcn_s_setprio(1);
        MM16(ahi, bhi, 4, 2);
        __builtin_amdgcn_s_setprio(0);
        BAR;

        // ---- phase 4: stage A(t+2); MFMA A1B0 (all regs); counted wait
        if (st2) STAGE_A2(c, t + 2)
        BAR;
        __builtin_amdgcn_s_setprio(1);
        MM16(ahi, blo, 4, 0);
        __builtin_amdgcn_s_setprio(0);
        if (st2) { asm volatile("s_waitcnt vmcnt(8)" ::: "memory"); }
        else     { asm volatile("s_waitcnt vmcnt(0)" ::: "memory"); }
        BAR;
    }

    // epilogue: D layout col = lane&15, row = (lane>>4)*4 + reg
#pragma unroll
    for (int m = 0; m < 8; ++m) {
        long r0 = bm + wm * 128 + m * 16 + hi * 4;
#pragma unroll
        for (int n = 0; n < 4; ++n) {
            long cc = bn + wn * 64 + n * 16 + fr;
#pragma unroll
            for (int v = 0; v < 4; ++v) {
                if (C_BF16)
                    ((bf16_t*)Cp)[(r0 + v) * (long)ldc + cc] = (bf16_t)acc[m][n][v];
                else
                    ((float*)Cp)[(r0 + v) * (long)ldc + cc] = acc[m][n][v];
            }
        }
    }
#undef STAGE_A2
#undef STAGE_B2
#undef MM16
}

// ---------------------------------------------------------------------------
// RoPE in place on Q and K regions of QKV [4096][6144]. 4 pairs per thread.
__global__ __launch_bounds__(256)
void rope_qk_k(bf16_t* __restrict__ QKV, const int* __restrict__ pos) {
    int t = blockIdx.x * 256 + threadIdx.x;   // 2^20 threads
    int g = t & 15;            // 4-pair group: pairs 4g..4g+3
    int h = (t >> 4) & 15;
    int s = (t >> 8) & 2047;
    int b = t >> 19;
    long qa = ((long)(b * S_ + s)) * LDQ + h * DH_ + g * 8;
    long ka = qa + D_;
    float p = (float)pos[b * S_ + s];
    bf16x8 q = *(bf16x8*)(QKV + qa);
    bf16x8 k = *(bf16x8*)(QKV + ka);
#pragma unroll
    for (int e = 0; e < 4; ++e) {
        int i = g * 4 + e;     // pair index 0..63
        float invf = exp2f(-(float)i * 0.20762050593045702f);  // 10000^(-2i/128)
        float ang = p * invf;
        float sn, cs;
        __sincosf(ang, &sn, &cs);
        float q1 = (float)q[2 * e], q2 = (float)q[2 * e + 1];
        q[2 * e]     = (bf16_t)(q1 * cs - q2 * sn);
        q[2 * e + 1] = (bf16_t)(q1 * sn + q2 * cs);
        float k1 = (float)k[2 * e], k2 = (float)k[2 * e + 1];
        k[2 * e]     = (bf16_t)(k1 * cs - k2 * sn);
        k[2 * e + 1] = (bf16_t)(k1 * sn + k2 * cs);
    }
    *(bf16x8*)(QKV + qa) = q;
    *(bf16x8*)(QKV + ka) = k;
}

// ---------------------------------------------------------------------------
// V reshape+transpose from QKV cols [4096,6144) -> Vt (B,H,dh,S)
__global__ __launch_bounds__(256)
void transpose_v_k(const bf16_t* __restrict__ QKV, bf16_t* __restrict__ Vt) {
    __shared__ bf16_t tile[64][80];
    int t = threadIdx.x;
    int bh = blockIdx.z;
    int b = bh >> 4, h = bh & 15;
    long s0 = (long)blockIdx.x * 64;
    int d0 = blockIdx.y * 64;
    const bf16_t* src = QKV + ((long)b * S_ + s0) * LDQ + 2 * D_ + h * DH_ + d0;
#pragma unroll
    for (int p = 0; p < 2; ++p) {
        int r = (t >> 3) + p * 32;
        int c = (t & 7) * 8;
        *(bf16x8*)&tile[r][c] = *(const bf16x8*)&src[(long)r * LDQ + c];
    }
    __syncthreads();
    bf16_t* dst = Vt + ((long)bh * DH_ + d0) * S_ + s0;
#pragma unroll
    for (int p = 0; p < 2; ++p) {
        int d = (t >> 3) + p * 32;
        int c = (t & 7) * 8;
        bf16x8 v;
#pragma unroll
        for (int e = 0; e < 8; ++e) v[e] = tile[c + e][d];
        *(bf16x8*)&dst[(long)d * S_ + c] = v;
    }
}

// ---------------------------------------------------------------------------
// swizzled LDS frag read: logical (row, ecol..ecol+7) of a [128][128] bf16 tile
__device__ __forceinline__ bf16x8 ldsw(const bf16_t* p, int row, int ecol) {
    return *(const bf16x8*)(p + row * 128 + (ecol ^ ((row & 7) << 3)));
}

// ---------------------------------------------------------------------------
// Fused causal flash attention, K/V double-buffered with counted vmcnt (T3/T4).
// Grid 512 = (qi heavy-first, b, h); 512 threads = 8 waves x 16 q-rows.
__global__ __launch_bounds__(512, 1)
void flash_attn_k(const bf16_t* __restrict__ QKV, const bf16_t* __restrict__ Vt,
                  bf16_t* __restrict__ O) {
    __shared__ bf16_t Ksh[2][128 * 128];
    __shared__ bf16_t Vsh[2][128 * 128];
    __shared__ bf16_t Psh[128 * 128];      // Q staging, then P

    const int tid  = threadIdx.x;
    const int w    = tid >> 6;
    const int lane = tid & 63;
    const int fr   = lane & 15;
    const int hi   = lane >> 4;
    const int hi8  = hi * 8;
    const int hi4  = hi * 4;
    const int w16  = w * 16;

    const int bid = blockIdx.x;
    const int qi  = 15 - (bid >> 5);      // heavy q-tiles first
    const int bh  = bid & 31;
    const int b   = bh >> 4;
    const int h   = bh & 15;
    const long bS   = (long)b * S_;
    const int  qoff = h * DH_;
    const int  koff = D_ + h * DH_;
    const long vbase = (long)bh * DH_;

    // ---- stage Q -> Psh, and K(0),V(0) -> buf 0
#pragma unroll
    for (int p = 0; p < 4; ++p) {
        int idx = p * 512 + tid;
        int row = idx >> 4;
        int sl  = (idx & 15) ^ (row & 7);
        gload_lds16(QKV + (bS + qi * 128 + row) * (long)LDQ + qoff + sl * 8,
                    &Psh[(p * 512 + w * 64) * 8]);
    }
#pragma unroll
    for (int p = 0; p < 4; ++p) {
        int idx = p * 512 + tid;
        int row = idx >> 4;
        int sl  = (idx & 15) ^ (row & 7);
        gload_lds16(QKV + (bS + row) * (long)LDQ + koff + sl * 8,
                    &Ksh[0][(p * 512 + w * 64) * 8]);
        gload_lds16(Vt + (vbase + row) * S_ + sl * 8,
                    &Vsh[0][(p * 512 + w * 64) * 8]);
    }
    asm volatile("s_waitcnt vmcnt(8)" ::: "memory");   // Q landed; K0/V0 in flight
    __builtin_amdgcn_s_barrier();
    asm volatile("" ::: "memory");

    bf16x8 qfrag[4];
#pragma unroll
    for (int kk = 0; kk < 4; ++kk)
        qfrag[kk] = ldsw(Psh, w16 + fr, kk * 32 + hi8);

    f32x4 o[8] = {};
    float m_run[4] = {-3.0e38f, -3.0e38f, -3.0e38f, -3.0e38f};
    float l_run[4] = {};

    const float SC = 0.08838834764831845f * 1.4426950408889634f; // /sqrt(dh)*log2e

    for (int kt = 0; kt <= qi; ++kt) {
        const int buf = kt & 1;
        // ---- prefetch next tile into other buffer; counted vmcnt (never 0 mid-loop)
        if (kt < qi) {
#pragma unroll
            for (int p = 0; p < 4; ++p) {
                int idx = p * 512 + tid;
                int row = idx >> 4;
                int sl  = (idx & 15) ^ (row & 7);
                gload_lds16(QKV + (bS + (kt + 1) * 128 + row) * (long)LDQ + koff + sl * 8,
                            &Ksh[buf ^ 1][(p * 512 + w * 64) * 8]);
                gload_lds16(Vt + (vbase + row) * S_ + (kt + 1) * 128 + sl * 8,
                            &Vsh[buf ^ 1][(p * 512 + w * 64) * 8]);
            }
            asm volatile("s_waitcnt vmcnt(8)" ::: "memory");  // K(kt),V(kt) done
        } else {
            asm volatile("s_waitcnt vmcnt(0)" ::: "memory");
        }
        __builtin_amdgcn_s_barrier();
        asm volatile("" ::: "memory");

        // ---- QK^T: wave's 16 q-rows x 128 kv-cols
        f32x4 sc[8];
#pragma unroll
        for (int j = 0; j < 8; ++j) {
            f32x4 z = {};
#pragma unroll
            for (int kk = 0; kk < 4; ++kk)
                z = __builtin_amdgcn_mfma_f32_16x16x32_bf16(
                        qfrag[kk], ldsw(Ksh[buf], j * 16 + fr, kk * 32 + hi8), z, 0, 0, 0);
            sc[j] = z;
        }

        // ---- scale + causal mask (diagonal tile only)
        const bool diag = (kt == qi);
#pragma unroll
        for (int j = 0; j < 8; ++j)
#pragma unroll
            for (int v = 0; v < 4; ++v) {
                float x = sc[j][v] * SC;
                if (diag && (j * 16 + fr > w16 + hi4 + v)) x = -3.0e38f;
                sc[j][v] = x;
            }

        // ---- online softmax (log2 domain), rows = w16+hi4+v
        float fsc[4];
#pragma unroll
        for (int v = 0; v < 4; ++v) {
            float m = fmaxf(fmaxf(fmaxf(sc[0][v], sc[1][v]), fmaxf(sc[2][v], sc[3][v])),
                            fmaxf(fmaxf(sc[4][v], sc[5][v]), fmaxf(sc[6][v], sc[7][v])));
            m = fmaxf(m, __shfl_xor(m, 1));
            m = fmaxf(m, __shfl_xor(m, 2));
            m = fmaxf(m, __shfl_xor(m, 4));
            m = fmaxf(m, __shfl_xor(m, 8));
            float mn = fmaxf(m_run[v], m);
            fsc[v] = exp2f(m_run[v] - mn);
            m_run[v] = mn;
            l_run[v] *= fsc[v];
        }
#pragma unroll
        for (int j2 = 0; j2 < 8; ++j2)
#pragma unroll
            for (int v = 0; v < 4; ++v) o[j2][v] *= fsc[v];

        // ---- P = exp2(sc - m) -> own wave's rows of Psh (swizzled)
#pragma unroll
        for (int j = 0; j < 8; ++j)
#pragma unroll
            for (int v = 0; v < 4; ++v) {
                float p = exp2f(sc[j][v] - m_run[v]);
                l_run[v] += p;
                int row = w16 + hi4 + v;
                int col = j * 16 + fr;
                Psh[row * 128 + (col ^ ((row & 7) << 3))] = (bf16_t)p;
            }

        asm volatile("s_waitcnt lgkmcnt(0)" ::: "memory");
        __builtin_amdgcn_sched_barrier(0);

        // ---- PV: O += P[16x128] * V[128x128]  (Vsh is V^T [dh][kv])
        bf16x8 pa[4];
#pragma unroll
        for (int kk = 0; kk < 4; ++kk)
            pa[kk] = ldsw(Psh, w16 + fr, kk * 32 + hi8);
#pragma unroll
        for (int j2 = 0; j2 < 8; ++j2)
#pragma unroll
            for (int kk = 0; kk < 4; ++kk)
                o[j2] = __builtin_amdgcn_mfma_f32_16x16x32_bf16(
                            pa[kk], ldsw(Vsh[buf], j2 * 16 + fr, kk * 32 + hi8), o[j2], 0, 0, 0);

        asm volatile("" ::: "memory");
        __builtin_amdgcn_s_barrier();       // protect buf^1 for next prefetch
        asm volatile("" ::: "memory");
    }

    // ---- epilogue: normalize and store AttnOut (B,S,H*dh)
#pragma unroll
    for (int v = 0; v < 4; ++v) {
        float l = l_run[v];
        l += __shfl_xor(l, 1);
        l += __shfl_xor(l, 2);
        l += __shfl_xor(l, 4);
        l += __shfl_xor(l, 8);
        l_run[v] = 1.0f / l;
    }
    const long orow = bS + qi * 128 + w16 + hi4;
#pragma unroll
    for (int j2 = 0; j2 < 8; ++j2)
#pragma unroll
        for (int v = 0; v < 4; ++v)
            O[(orow + v) * D_ + qoff + j2 * 16 + fr] = (bf16_t)(o[j2][v] * l_run[v]);
}

// ---------------------------------------------------------------------------
extern "C" void kernel_launch(void* const* d_in, const int* in_sizes, int n_in,
                              void* d_out, int out_size, void* d_ws, size_t ws_size,
                              hipStream_t stream) {
    const float* in_features = (const float*)d_in[0];
    const int*   positions   = (const int*)d_in[1];
    // d_in[2] = mask (analytic causal)
    const float* Wq = (const float*)d_in[3];
    const float* Wk = (const float*)d_in[4];
    const float* Wv = (const float*)d_in[5];
    const float* Wo = (const float*)d_in[6];
    float* out = (float*)d_out;

    const size_t SZ_X   = (size_t)B_ * S_ * D_ * 2;    // 16.78 MB
    const size_t SZ_W   = (size_t)D_ * D_ * 2;         // 8.39 MB
    const size_t SZ_QKV = (size_t)B_ * S_ * LDQ * 2;   // 50.33 MB
    if (ws_size < SZ_X * 3 + SZ_W * 4 + SZ_QKV) return;  // 134.2 MB

    char* w = (char*)d_ws;
    bf16_t* Xb      = (bf16_t*)w;   w += SZ_X;
    bf16_t* Wqkv    = (bf16_t*)w;   w += SZ_W * 3;
    bf16_t* Wob     = (bf16_t*)w;   w += SZ_W;
    bf16_t* QKV     = (bf16_t*)w;   w += SZ_QKV;
    bf16_t* Vt      = (bf16_t*)w;   w += SZ_X;
    bf16_t* AttnOut = (bf16_t*)w;   w += SZ_X;

    // 1. fused casts (X, Wq|Wk|Wv -> concat, Wo)
    cast_all_k<<<24576, 256, 0, stream>>>(in_features, Wq, Wk, Wv, Wo, Xb, Wqkv, Wob);

    // 2. merged QKV projection: [4096][6144] = X * Wqkv^T  (256^2 m201 schedule)
    gemm8<true><<<384, 512, 0, stream>>>(Xb, D_, Wqkv, D_, QKV, LDQ, D_, 24);

    // 3. RoPE in place on Q,K regions
    rope_qk_k<<<4096, 256, 0, stream>>>(QKV, positions);
    // 4. V transpose to (B,H,dh,S)
    transpose_v_k<<<dim3(32, 2, 32), 256, 0, stream>>>(QKV, Vt);

    // 5. fused causal flash attention -> AttnOut (B,S,H*dh)
    flash_attn_k<<<512, 512, 0, stream>>>(QKV, Vt, AttnOut);

    // 6. output projection -> fp32 d_out  (same kernel, 16x8 = 128 blocks)
    gemm8<false><<<128, 512, 0, stream>>>(AttnOut, D_, Wob, D_, out, D_, D_, 8);
}